// Round 6
// baseline (986.272 us; speedup 1.0000x reference)
//
#include <hip/hip_runtime.h>
#include <hip/hip_bf16.h>

#define NN   13824     // 24^3 neurons
#define BB   256       // batch
#define KDIM 512       // input dim
#define ODIM 1000      // output dim
#define CUBE 24
#define KS   16        // out-gemm split-K
#define ASTR 872       // outgemm LDS A row stride in shorts (1744B, %128B!=0 ok, no XOR)
#define XSTR 520       // xproj LDS A row stride in shorts (1040B = 260 dw, %32=4)

typedef short bf8 __attribute__((ext_vector_type(8)));     // 8 bf16 (4 VGPRs)
typedef float f32x4 __attribute__((ext_vector_type(4)));   // MFMA acc

__device__ __forceinline__ float fast_tanh(float a) {
    float e = __expf(2.0f * a);
    return 1.0f - 2.0f / (e + 1.0f);
}
__device__ __forceinline__ float bf_lo(unsigned u) { return __uint_as_float(u << 16); }
__device__ __forceinline__ float bf_hi(unsigned u) { return __uint_as_float(u & 0xffff0000u); }
__device__ __forceinline__ unsigned short bf_rne(float f) {
    unsigned u = __float_as_uint(f);
    u += 0x7fffu + ((u >> 16) & 1u);
    return (unsigned short)(u >> 16);
}
// packed fp32x2 -> bf16x2 via v_cvt_pk_bf16_f32 (one inst on gfx950)
__device__ __forceinline__ unsigned pk_bf16(float lo, float hi) {
    union { __hip_bfloat162 h; unsigned u; } cv;
    cv.h = __float22bfloat162_rn(make_float2(lo, hi));
    return cv.u;
}

// ---------------------------------------------------------------------------
// x (fp32 [256][512]) -> x_bf (bf16 packed dwords)
// ---------------------------------------------------------------------------
__global__ __launch_bounds__(256) void xbf_kernel(
    const float* __restrict__ x, unsigned* __restrict__ xb)
{
    int i = blockIdx.x * 256 + threadIdx.x;
    float2 v = *(const float2*)&x[(size_t)i * 2];
    xb[i] = pk_bf16(v.x, v.y);
}

// ---------------------------------------------------------------------------
// xproj v2: LDS-staged A (same fix as outgemm v6b -- w_in rows were read as
// 16 concurrent 2KB-strided streams, one line per row per instr -> L3
// request-rate bound at 53us). Stage the 16x512 A panel once per block as
// bf16 (16.6KB LDS, stride 520 shorts: start banks (4*l16+4*quad)%32 cover
// the 8 multiple-of-4 positions x8 lanes = uniform 8/bank = b128 minimum).
// B (xbf, 256KB L2-resident) keeps the depth-1 register pipeline.
// ---------------------------------------------------------------------------
__global__ __launch_bounds__(256) void xproj_mfma(
    const float* __restrict__ w_in, const float* __restrict__ bias,
    const short* __restrict__ xbf, unsigned short* __restrict__ xp,
    unsigned short* __restrict__ h1)
{
    __shared__ unsigned short As[16 * XSTR];
    const int tid = threadIdx.x, w = tid >> 6, lane = tid & 63;
    const int quad = lane >> 4, l16 = lane & 15;
    const int n0 = blockIdx.x * 16;

    // ---- stage A: 4 whole rows per wave, 1KB-contiguous reads ----
#pragma unroll
    for (int rr = 0; rr < 4; ++rr) {
        const int row = w * 4 + rr;
        const float* __restrict__ src = &w_in[(size_t)(n0 + row) * KDIM];
#pragma unroll
        for (int c = 0; c < 2; ++c) {
            const int col = c * 256 + lane * 4;
            float4 v = *(const float4*)&src[col];
            uint2 pk2 = make_uint2(pk_bf16(v.x, v.y), pk_bf16(v.z, v.w));
            *(uint2*)&As[row * XSTR + col] = pk2;
        }
    }
    __syncthreads();

    f32x4 acc[4] = {};

    int ka = quad * 8;
    bf8 bb[4];
#pragma unroll
    for (int j = 0; j < 4; ++j)
        bb[j] = *(const bf8*)&xbf[(size_t)(w * 64 + j * 16 + l16) * KDIM + ka];

    for (int it = 0; it < 16; ++it) {
        bf8 nb[4] = {};
        if (it < 15) {
            const int nka = ka + 32;
#pragma unroll
            for (int j = 0; j < 4; ++j)
                nb[j] = *(const bf8*)&xbf[(size_t)(w * 64 + j * 16 + l16) * KDIM + nka];
        }
        bf8 af = *(const bf8*)&As[l16 * XSTR + it * 32 + quad * 8];
#pragma unroll
        for (int j = 0; j < 4; ++j)
            acc[j] = __builtin_amdgcn_mfma_f32_16x16x32_bf16(af, bb[j], acc[j], 0, 0, 0);
#pragma unroll
        for (int j = 0; j < 4; ++j) bb[j] = nb[j];
        ka += 32;
    }

#pragma unroll
    for (int j = 0; j < 4; ++j) {
        const int b = w * 64 + j * 16 + l16;
#pragma unroll
        for (int r = 0; r < 4; ++r) {
            const int n = n0 + quad * 4 + r;
            const float v = acc[j][r] + bias[n];
            xp[(size_t)n * BB + b] = bf_rne(v);
            h1[(size_t)n * BB + b] = bf_rne(fast_tanh(v));
        }
    }
}

// ---------------------------------------------------------------------------
// Recurrent step v8: halo-tiled LDS. v4-v7 were all ~15us regardless of
// occupancy/registers/prefetch -- the invariant was the ~85MB/step of
// beyond-L1 traffic (12x halo re-read), served from L3 because per-XCD L2s
// flush at kernel boundaries. v8: block = 4x4x4 output tile x 1 batch-half;
// stage the 6x6x6 halo cube ONCE into LDS (216 rows x 256B = 55.3KB,
// zero-filled outside the cube; per-wave runs of 6 consecutive rows = 3KB
// contiguous streams), then compute entirely from LDS with the proven v6
// float2 ring. Traffic: 3.4x amp -> ~24MB/step reads. Grid 216 tiles x 2
// halves = 432 blocks, 2 blocks/CU (LDS-limited). Bank math: Ls[r*64+lane]
// -> 2 lanes/bank on both ds_write and ds_read (free, m136).
// ---------------------------------------------------------------------------
__device__ __forceinline__ void ldplane_lds(
    const unsigned* __restrict__ Ls, int zo, int yo, int p, int lane,
    float2* w9)
{
#pragma unroll
    for (int j = 0; j < 9; ++j) {
        const int dz = j / 3, dy = j % 3;
        const unsigned v = Ls[(((zo + dz) * 6 + (yo + dy)) * 6 + p) * 64 + lane];
        w9[j] = make_float2(bf_lo(v), bf_hi(v));
    }
}

__global__ __launch_bounds__(256) void step_kernel(
    const unsigned* __restrict__ hprev, const unsigned* __restrict__ xp,
    const float* __restrict__ wl, unsigned* __restrict__ hnext)
{
    __shared__ unsigned Ls[216 * 64];    // 6x6x6 halo rows x 64 dwords
    const int tid  = threadIdx.x;
    const int w    = __builtin_amdgcn_readfirstlane(tid >> 6);  // 0..3
    const int lane = tid & 63;

    const int bid  = blockIdx.x;
    const int half = bid & 1;
    const int t    = bid >> 1;          // 0..215
    const int tx   = t % 6;
    const int ty   = (t / 6) % 6;
    const int tz   = t / 36;
    const int z0 = tz * 4, y0 = ty * 4, x0 = tx * 4;
    const int dof = half * 64 + lane;   // dword offset (2 batch elems)

    // ---- stage halo cube: 54 rows per wave (runs of 6 consecutive n) ----
#pragma unroll 6
    for (int i = 0; i < 54; ++i) {
        const int r  = w * 54 + i;      // wave-uniform
        const int lx = r % 6, ly = (r / 6) % 6, lz = r / 36;
        const int z = z0 - 1 + lz, y = y0 - 1 + ly, x = x0 - 1 + lx;
        const bool valid = (z >= 0) & (z < CUBE) & (y >= 0) & (y < CUBE) &
                           (x >= 0) & (x < CUBE);
        unsigned v = 0u;
        if (valid) v = hprev[(size_t)((z * 24 + y) * 24 + x) * 128 + dof];
        Ls[r * 64 + lane] = v;
    }
    __syncthreads();

    // ---- compute: wave w = z-slice zo=w; 4 y-lines; x-sweep of 4 ----
    const int zo = w;
    float2 win[5][9];
#pragma unroll 1
    for (int yo = 0; yo < 4; ++yo) {
        ldplane_lds(Ls, zo, yo, 0, lane, win[0]);
        ldplane_lds(Ls, zo, yo, 1, lane, win[1]);
        ldplane_lds(Ls, zo, yo, 2, lane, win[2]);
        ldplane_lds(Ls, zo, yo, 3, lane, win[3]);

#pragma unroll
        for (int xo = 0; xo < 4; ++xo) {
            if (xo <= 1)
                ldplane_lds(Ls, zo, yo, xo + 4, lane, win[(xo + 4) % 5]);

            const int n = ((z0 + zo) * 24 + (y0 + yo)) * 24 + (x0 + xo);
            const float* __restrict__ wn = &wl[(size_t)n * 27];
            const unsigned xpv = xp[(size_t)n * 128 + dof];
            float2 acc = make_float2(bf_lo(xpv), bf_hi(xpv));

            const float2* pm = win[xo % 5];
            const float2* pc = win[(xo + 1) % 5];
            const float2* pp = win[(xo + 2) % 5];
#pragma unroll
            for (int j = 0; j < 9; ++j) {
                const float w0 = wn[3 * j + 0];
                const float w1 = wn[3 * j + 1];
                const float w2 = wn[3 * j + 2];
                acc.x += w0 * pm[j].x + w1 * pc[j].x + w2 * pp[j].x;
                acc.y += w0 * pm[j].y + w1 * pc[j].y + w2 * pp[j].y;
            }
            hnext[(size_t)n * 128 + dof] =
                pk_bf16(fast_tanh(acc.x), fast_tanh(acc.y));
        }
    }
}

// ---------------------------------------------------------------------------
// Transpose h[k][b] -> hT[b][k] (bf16), 64x64 tiles via LDS.
// ---------------------------------------------------------------------------
__global__ __launch_bounds__(256) void transpose_kernel(
    const unsigned* __restrict__ h32, unsigned* __restrict__ hT32)
{
    __shared__ unsigned short T[64][66];
    const int tid = threadIdx.x;
    const int rr = tid >> 2, g = tid & 3;
    const int k0 = blockIdx.x * 64, b0 = blockIdx.y * 64;
#pragma unroll
    for (int i = 0; i < 8; ++i) {
        unsigned d = h32[(size_t)(k0 + rr) * 128 + b0 / 2 + g * 8 + i];
        const int bl = (g * 8 + i) * 2;
        T[bl][rr]     = (unsigned short)(d & 0xffffu);
        T[bl + 1][rr] = (unsigned short)(d >> 16);
    }
    __syncthreads();
#pragma unroll
    for (int i = 0; i < 8; ++i) {
        const int kl = (g * 8 + i) * 2;
        unsigned d = (unsigned)T[rr][kl] | ((unsigned)T[rr][kl + 1] << 16);
        hT32[(size_t)(b0 + rr) * (NN / 2) + k0 / 2 + g * 8 + i] = d;
    }
}

// ---------------------------------------------------------------------------
// Output GEMM v6b (round-5, proven): LDS-staged A, padded stride, no XOR.
// Block = 32o x 256b x 864k; A staged once (whole rows, 1KB-contiguous);
// B (hT) depth-1 register pipeline; blockIdx.x = K-chunk (XCD affinity).
// ---------------------------------------------------------------------------
__global__ __launch_bounds__(256) void outgemm_mfma(
    const float* __restrict__ wout, const short* __restrict__ hT,
    float* __restrict__ part)
{
    __shared__ unsigned short As[32 * ASTR];
    const int tid = threadIdx.x, w = tid >> 6, lane = tid & 63;
    const int quad = lane >> 4, l16 = lane & 15;
    const int kb = blockIdx.x * (NN / KS);    // 864-wide K chunk
    const int o0 = blockIdx.y * 32;
    const int b0 = w * 64;

    // ---- stage A: 8 rows per wave, 1KB-contiguous global reads ----
#pragma unroll
    for (int rr = 0; rr < 8; ++rr) {
        const int row = w * 8 + rr;
        const int o = o0 + row;
        const float* __restrict__ src = &wout[(size_t)o * NN + kb];
#pragma unroll
        for (int c = 0; c < 4; ++c) {
            const int col = c * 256 + lane * 4;     // floats within row
            if (c < 3 || lane < 24) {               // 864 = 3*256 + 96
                float4 v = {0.f, 0.f, 0.f, 0.f};
                if (o < ODIM) v = *(const float4*)&src[col];
                uint2 pk2 = make_uint2(pk_bf16(v.x, v.y), pk_bf16(v.z, v.w));
                *(uint2*)&As[(unsigned)row * ASTR + (unsigned)col] = pk2;
            }
        }
    }
    __syncthreads();

    // ---- compute: 27 kc of K=32; depth-1 B prefetch (registers) ----
    f32x4 acc[2][4] = {};

    bf8 bb[4];
    {
        const int ka = kb + quad * 8;
#pragma unroll
        for (int j = 0; j < 4; ++j)
            bb[j] = *(const bf8*)&hT[(size_t)(b0 + j * 16 + l16) * NN + ka];
    }

    const int r0 = l16, r1 = 16 + l16;

    for (int kc = 0; kc < 27; ++kc) {
        bf8 nb[4] = {};
        if (kc < 26) {
            const int ka = kb + (kc + 1) * 32 + quad * 8;
#pragma unroll
            for (int j = 0; j < 4; ++j)
                nb[j] = *(const bf8*)&hT[(size_t)(b0 + j * 16 + l16) * NN + ka];
        }
        const int cs = kc * 32 + quad * 8;           // short offset in row
        bf8 a0 = *(const bf8*)&As[(unsigned)r0 * ASTR + (unsigned)cs];
        bf8 a1 = *(const bf8*)&As[(unsigned)r1 * ASTR + (unsigned)cs];
#pragma unroll
        for (int j = 0; j < 4; ++j) {
            acc[0][j] = __builtin_amdgcn_mfma_f32_16x16x32_bf16(a0, bb[j], acc[0][j], 0, 0, 0);
            acc[1][j] = __builtin_amdgcn_mfma_f32_16x16x32_bf16(a1, bb[j], acc[1][j], 0, 0, 0);
        }
#pragma unroll
        for (int j = 0; j < 4; ++j) bb[j] = nb[j];
    }

#pragma unroll
    for (int i = 0; i < 2; ++i)
#pragma unroll
        for (int j = 0; j < 4; ++j) {
            const int b = b0 + j * 16 + l16;
#pragma unroll
            for (int r = 0; r < 4; ++r) {
                const int o = o0 + i * 16 + quad * 4 + r;
                part[((size_t)blockIdx.x * 1024 + o) * BB + b] = acc[i][j][r];
            }
        }
}

// out[b*1000+o] = bias[o] + sum_kc part[kc][o][b]; block per o, lanes = b.
__global__ __launch_bounds__(256) void reduce_kernel(
    const float* __restrict__ part, const float* __restrict__ bias,
    float* __restrict__ out)
{
    const int o = blockIdx.x, b = threadIdx.x;
    float s = bias[o];
#pragma unroll
    for (int kc = 0; kc < KS; ++kc)
        s += part[((size_t)kc * 1024 + o) * BB + b];
    out[(size_t)b * ODIM + o] = s;
}

extern "C" void kernel_launch(void* const* d_in, const int* in_sizes, int n_in,
                              void* d_out, int out_size, void* d_ws, size_t ws_size,
                              hipStream_t stream)
{
    const float* x       = (const float*)d_in[0];
    const float* w_in    = (const float*)d_in[1];
    const float* b_in    = (const float*)d_in[2];
    const float* w_local = (const float*)d_in[3];
    const float* w_out   = (const float*)d_in[4];
    const float* b_out   = (const float*)d_in[5];
    float* out = (float*)d_out;

    char* p = (char*)d_ws;
    unsigned short* xp_bf = (unsigned short*)p;          p += (size_t)NN * BB * 2;
    unsigned short* hA    = (unsigned short*)p;          p += (size_t)NN * BB * 2;
    unsigned short* hB    = (unsigned short*)p;          p += (size_t)NN * BB * 2;
    unsigned short* hT    = (unsigned short*)p;          p += (size_t)NN * BB * 2;
    unsigned short* x_bf  = (unsigned short*)p;          p += (size_t)BB * KDIM * 2;
    float*          part  = (float*)p;                   // KS*1024*BB floats

    xbf_kernel<<<256, 256, 0, stream>>>(x, (unsigned*)x_bf);
    xproj_mfma<<<864, 256, 0, stream>>>(w_in, b_in, (const short*)x_bf, xp_bf, hA);

    const unsigned* hp = (const unsigned*)hA;
    unsigned* hn = (unsigned*)hB;
    for (int s = 0; s < 29; ++s) {          // 29 odd -> final state in hB
        step_kernel<<<432, 256, 0, stream>>>(hp, (const unsigned*)xp_bf, w_local, hn);
        unsigned* t = (unsigned*)hp; hp = hn; hn = t;
    }

    transpose_kernel<<<dim3(216, 4), 256, 0, stream>>>(hp, (unsigned*)hT);
    outgemm_mfma<<<dim3(KS, 32), 256, 0, stream>>>(w_out, (const short*)hT, part);
    reduce_kernel<<<ODIM, 256, 0, stream>>>(part, b_out, out);
}

// Round 7
// 553.778 us; speedup vs baseline: 1.7810x; 1.7810x over previous
//
#include <hip/hip_runtime.h>
#include <hip/hip_bf16.h>

#define NN   13824     // 24^3 neurons
#define BB   256       // batch
#define KDIM 512       // input dim
#define ODIM 1000      // output dim
#define CUBE 24
#define KS   16        // out-gemm split-K
#define XSTR 520       // xproj LDS A row stride in shorts (1040B = 260 dw, %32=4)
#define OSTR 456       // outgemm LDS A row stride in shorts (912B = 228 dw, %32=4)

typedef short bf8 __attribute__((ext_vector_type(8)));     // 8 bf16 (4 VGPRs)
typedef float f32x4 __attribute__((ext_vector_type(4)));   // MFMA acc

__device__ __forceinline__ float fast_tanh(float a) {
    float e = __expf(2.0f * a);
    return 1.0f - 2.0f / (e + 1.0f);
}
__device__ __forceinline__ float bf_lo(unsigned u) { return __uint_as_float(u << 16); }
__device__ __forceinline__ float bf_hi(unsigned u) { return __uint_as_float(u & 0xffff0000u); }
__device__ __forceinline__ unsigned short bf_rne(float f) {
    unsigned u = __float_as_uint(f);
    u += 0x7fffu + ((u >> 16) & 1u);
    return (unsigned short)(u >> 16);
}
// packed fp32x2 -> bf16x2 via v_cvt_pk_bf16_f32 (one inst on gfx950)
__device__ __forceinline__ unsigned pk_bf16(float lo, float hi) {
    union { __hip_bfloat162 h; unsigned u; } cv;
    cv.h = __float22bfloat162_rn(make_float2(lo, hi));
    return cv.u;
}

// ---------------------------------------------------------------------------
// x (fp32 [256][512]) -> x_bf (bf16 packed dwords)
// ---------------------------------------------------------------------------
__global__ __launch_bounds__(256) void xbf_kernel(
    const float* __restrict__ x, unsigned* __restrict__ xb)
{
    int i = blockIdx.x * 256 + threadIdx.x;
    float2 v = *(const float2*)&x[(size_t)i * 2];
    xb[i] = pk_bf16(v.x, v.y);
}

// ---------------------------------------------------------------------------
// xproj v2 (round-6, passed): LDS-staged A panel, whole-row reads.
// ---------------------------------------------------------------------------
__global__ __launch_bounds__(256) void xproj_mfma(
    const float* __restrict__ w_in, const float* __restrict__ bias,
    const short* __restrict__ xbf, unsigned short* __restrict__ xp,
    unsigned short* __restrict__ h1)
{
    __shared__ unsigned short As[16 * XSTR];
    const int tid = threadIdx.x, w = tid >> 6, lane = tid & 63;
    const int quad = lane >> 4, l16 = lane & 15;
    const int n0 = blockIdx.x * 16;

    // ---- stage A: 4 whole rows per wave, 1KB-contiguous reads ----
#pragma unroll
    for (int rr = 0; rr < 4; ++rr) {
        const int row = w * 4 + rr;
        const float* __restrict__ src = &w_in[(size_t)(n0 + row) * KDIM];
#pragma unroll
        for (int c = 0; c < 2; ++c) {
            const int col = c * 256 + lane * 4;
            float4 v = *(const float4*)&src[col];
            uint2 pk2 = make_uint2(pk_bf16(v.x, v.y), pk_bf16(v.z, v.w));
            *(uint2*)&As[row * XSTR + col] = pk2;
        }
    }
    __syncthreads();

    f32x4 acc[4] = {};

    int ka = quad * 8;
    bf8 bb[4];
#pragma unroll
    for (int j = 0; j < 4; ++j)
        bb[j] = *(const bf8*)&xbf[(size_t)(w * 64 + j * 16 + l16) * KDIM + ka];

    for (int it = 0; it < 16; ++it) {
        bf8 nb[4] = {};
        if (it < 15) {
            const int nka = ka + 32;
#pragma unroll
            for (int j = 0; j < 4; ++j)
                nb[j] = *(const bf8*)&xbf[(size_t)(w * 64 + j * 16 + l16) * KDIM + nka];
        }
        bf8 af = *(const bf8*)&As[l16 * XSTR + it * 32 + quad * 8];
#pragma unroll
        for (int j = 0; j < 4; ++j)
            acc[j] = __builtin_amdgcn_mfma_f32_16x16x32_bf16(af, bb[j], acc[j], 0, 0, 0);
#pragma unroll
        for (int j = 0; j < 4; ++j) bb[j] = nb[j];
        ka += 32;
    }

#pragma unroll
    for (int j = 0; j < 4; ++j) {
        const int b = w * 64 + j * 16 + l16;
#pragma unroll
        for (int r = 0; r < 4; ++r) {
            const int n = n0 + quad * 4 + r;
            const float v = acc[j][r] + bias[n];
            xp[(size_t)n * BB + b] = bf_rne(v);
            h1[(size_t)n * BB + b] = bf_rne(fast_tanh(v));
        }
    }
}

// ---------------------------------------------------------------------------
// Recurrent step v6 (round-2/5 proven best, 14.9us): float2 ring-5, x-chunk
// 6, 4-wave blocks pairing two adjacent y-lines (L1 sharing). 1152 blocks,
// bid&7 == z/3 -> XCD L2 slab pinning. v8 (halo-LDS) regressed 2x: step is
// latency/TLP-bound (18 waves/CU needed), NOT traffic-bound.
// ---------------------------------------------------------------------------
__device__ __forceinline__ void load_plane_f2(
    const unsigned* __restrict__ h32, int z, int y, int xx, int dof, float2* w9)
{
#pragma unroll
    for (int j = 0; j < 9; ++j) {
        const int dz = j / 3 - 1, dy = j % 3 - 1;
        const int zz = z + dz, yy = y + dy;
        const bool valid = (xx >= 0) & (xx < CUBE) & (zz >= 0) & (zz < CUBE) &
                           (yy >= 0) & (yy < CUBE);   // wave-uniform
        unsigned v = 0u;
        if (valid) v = h32[(size_t)((zz * 24 + yy) * 24 + xx) * 128 + dof];
        w9[j] = make_float2(bf_lo(v), bf_hi(v));
    }
}

__global__ __launch_bounds__(256) void step_kernel(
    const unsigned* __restrict__ hprev, const unsigned* __restrict__ xp,
    const float* __restrict__ wl, unsigned* __restrict__ hnext)
{
    const int tid  = threadIdx.x;
    const int wid  = __builtin_amdgcn_readfirstlane(tid >> 6);  // 0..3
    const int wvb  = wid & 1;          // batch half
    const int yoff = wid >> 1;         // y within the pair
    const int lane = tid & 63;

    const int bid   = blockIdx.x;
    const int zhi   = bid & 7;
    const int inner = bid >> 3;       // 0..143
    const int yp    = inner % 12;
    const int r     = inner / 12;     // 0..11
    const int xc    = r & 3;
    const int zlo   = r >> 2;
    const int z     = zhi * 3 + zlo;
    const int y     = yp * 2 + yoff;

    const int x0   = xc * 6;
    const int dof  = wvb * 64 + lane;  // dword offset (2 batch elems)

    float2 win[5][9];
    load_plane_f2(hprev, z, y, x0 - 1, dof, win[0]);
    load_plane_f2(hprev, z, y, x0,     dof, win[1]);
    load_plane_f2(hprev, z, y, x0 + 1, dof, win[2]);
    load_plane_f2(hprev, z, y, x0 + 2, dof, win[3]);

#pragma unroll
    for (int xi = 0; xi < 6; ++xi) {
        const int x = x0 + xi;
        if (xi <= 3)
            load_plane_f2(hprev, z, y, x + 3, dof, win[(xi + 4) % 5]);

        const int n = (z * 24 + y) * 24 + x;          // wave-uniform
        const float* __restrict__ wn = &wl[(size_t)n * 27];
        const unsigned xpv = xp[(size_t)n * 128 + dof];
        float2 acc = make_float2(bf_lo(xpv), bf_hi(xpv));

        const float2* pm = win[xi % 5];
        const float2* pc = win[(xi + 1) % 5];
        const float2* pp = win[(xi + 2) % 5];
#pragma unroll
        for (int j = 0; j < 9; ++j) {
            const float w0 = wn[3 * j + 0];
            const float w1 = wn[3 * j + 1];
            const float w2 = wn[3 * j + 2];
            acc.x += w0 * pm[j].x + w1 * pc[j].x + w2 * pp[j].x;
            acc.y += w0 * pm[j].y + w1 * pc[j].y + w2 * pp[j].y;
        }
        hnext[(size_t)n * 128 + dof] = pk_bf16(fast_tanh(acc.x), fast_tanh(acc.y));
    }
}

// ---------------------------------------------------------------------------
// Transpose h[k][b] -> hT[b][k] (bf16), 64x64 tiles via LDS.
// ---------------------------------------------------------------------------
__global__ __launch_bounds__(256) void transpose_kernel(
    const unsigned* __restrict__ h32, unsigned* __restrict__ hT32)
{
    __shared__ unsigned short T[64][66];
    const int tid = threadIdx.x;
    const int rr = tid >> 2, g = tid & 3;
    const int k0 = blockIdx.x * 64, b0 = blockIdx.y * 64;
#pragma unroll
    for (int i = 0; i < 8; ++i) {
        unsigned d = h32[(size_t)(k0 + rr) * 128 + b0 / 2 + g * 8 + i];
        const int bl = (g * 8 + i) * 2;
        T[bl][rr]     = (unsigned short)(d & 0xffffu);
        T[bl + 1][rr] = (unsigned short)(d >> 16);
    }
    __syncthreads();
#pragma unroll
    for (int i = 0; i < 8; ++i) {
        const int kl = (g * 8 + i) * 2;
        unsigned d = (unsigned)T[rr][kl] | ((unsigned)T[rr][kl + 1] << 16);
        hT32[(size_t)(b0 + rr) * (NN / 2) + k0 / 2 + g * 8 + i] = d;
    }
}

// ---------------------------------------------------------------------------
// Output GEMM v7: B-traffic fix on top of v6b's A-staging. v6b's 32-o tile
// re-read hT (7MB) 32x = 226MB L3 = the whole 51us. v7: o-tile 128 -> B
// traffic 8x7 = 56MB (~14us floor). A tile 128x864 bf16 = 221KB > LDS, so
// A staged in TWO K-phases (128x448 = 114KB live, barrier-separated).
// Block = 8 waves (512 thr), wave w = 128o x 32b (acc 8x2 f32x4 = 64 VGPR,
// b0 = w*32; B read once per block). Grid (16 K, 8 o) = 128 blocks.
// Bank math: OSTR=456 shorts = 228 dw, 228%32=4 -> row starts 4r%32, period
// 8 -> the 16-lane ds_read_b128 is 2-way (free, m136). part/KS unchanged.
// ---------------------------------------------------------------------------
__global__ __launch_bounds__(512) void outgemm_mfma(
    const float* __restrict__ wout, const short* __restrict__ hT,
    float* __restrict__ part)
{
    __shared__ unsigned short As[128 * OSTR];
    const int tid = threadIdx.x, w = tid >> 6, lane = tid & 63;
    const int quad = lane >> 4, l16 = lane & 15;
    const int kb = blockIdx.x * (NN / KS);    // 864-wide K chunk
    const int o0 = blockIdx.y * 128;
    const int b0 = w * 32;

    f32x4 acc[8][2] = {};

#pragma unroll 1
    for (int ph = 0; ph < 2; ++ph) {
        const int poff  = ph ? 448 : 0;       // K offset of this phase
        const int pcols = ph ? 416 : 448;     // floats per row this phase
        const int pkc   = ph ? 13 : 14;       // kc count (x32 = pcols)
        if (ph) __syncthreads();              // compute done before re-stage

        // ---- stage A: 16 rows/wave, 1KB-contiguous global reads ----
#pragma unroll 4
        for (int rr = 0; rr < 16; ++rr) {
            const int row = w * 16 + rr;
            const int o = o0 + row;
            const float* __restrict__ src = &wout[(size_t)o * NN + kb + poff];
            {
                const int col = lane * 4;
                float4 v = {0.f, 0.f, 0.f, 0.f};
                if (o < ODIM) v = *(const float4*)&src[col];
                *(uint2*)&As[row * OSTR + col] =
                    make_uint2(pk_bf16(v.x, v.y), pk_bf16(v.z, v.w));
            }
            {
                const int col = 256 + lane * 4;
                if (col < pcols) {
                    float4 v = {0.f, 0.f, 0.f, 0.f};
                    if (o < ODIM) v = *(const float4*)&src[col];
                    *(uint2*)&As[row * OSTR + col] =
                        make_uint2(pk_bf16(v.x, v.y), pk_bf16(v.z, v.w));
                }
            }
        }
        __syncthreads();

        // ---- compute pkc kc's; depth-1 B prefetch (dynamic loop) ----
        bf8 b0f, b1f;
        {
            const int ka = kb + poff + quad * 8;
            b0f = *(const bf8*)&hT[(size_t)(b0 + l16) * NN + ka];
            b1f = *(const bf8*)&hT[(size_t)(b0 + 16 + l16) * NN + ka];
        }
        for (int kc = 0; kc < pkc; ++kc) {
            bf8 n0 = {}, n1 = {};
            if (kc + 1 < pkc) {
                const int ka = kb + poff + (kc + 1) * 32 + quad * 8;
                n0 = *(const bf8*)&hT[(size_t)(b0 + l16) * NN + ka];
                n1 = *(const bf8*)&hT[(size_t)(b0 + 16 + l16) * NN + ka];
            }
            const int cs = kc * 32 + quad * 8;   // short offset within row
#pragma unroll
            for (int t = 0; t < 8; ++t) {
                bf8 af = *(const bf8*)&As[(t * 16 + l16) * OSTR + cs];
                acc[t][0] = __builtin_amdgcn_mfma_f32_16x16x32_bf16(af, b0f, acc[t][0], 0, 0, 0);
                acc[t][1] = __builtin_amdgcn_mfma_f32_16x16x32_bf16(af, b1f, acc[t][1], 0, 0, 0);
            }
            b0f = n0; b1f = n1;
        }
    }

    // ---- epilogue ----
#pragma unroll
    for (int t = 0; t < 8; ++t)
#pragma unroll
        for (int j = 0; j < 2; ++j) {
            const int b = b0 + j * 16 + l16;
#pragma unroll
            for (int r = 0; r < 4; ++r) {
                const int o = o0 + t * 16 + quad * 4 + r;
                part[((size_t)blockIdx.x * 1024 + o) * BB + b] = acc[t][j][r];
            }
        }
}

// out[b*1000+o] = bias[o] + sum_kc part[kc][o][b]; block per o, lanes = b.
__global__ __launch_bounds__(256) void reduce_kernel(
    const float* __restrict__ part, const float* __restrict__ bias,
    float* __restrict__ out)
{
    const int o = blockIdx.x, b = threadIdx.x;
    float s = bias[o];
#pragma unroll
    for (int kc = 0; kc < KS; ++kc)
        s += part[((size_t)kc * 1024 + o) * BB + b];
    out[(size_t)b * ODIM + o] = s;
}

extern "C" void kernel_launch(void* const* d_in, const int* in_sizes, int n_in,
                              void* d_out, int out_size, void* d_ws, size_t ws_size,
                              hipStream_t stream)
{
    const float* x       = (const float*)d_in[0];
    const float* w_in    = (const float*)d_in[1];
    const float* b_in    = (const float*)d_in[2];
    const float* w_local = (const float*)d_in[3];
    const float* w_out   = (const float*)d_in[4];
    const float* b_out   = (const float*)d_in[5];
    float* out = (float*)d_out;

    char* p = (char*)d_ws;
    unsigned short* xp_bf = (unsigned short*)p;          p += (size_t)NN * BB * 2;
    unsigned short* hA    = (unsigned short*)p;          p += (size_t)NN * BB * 2;
    unsigned short* hB    = (unsigned short*)p;          p += (size_t)NN * BB * 2;
    unsigned short* hT    = (unsigned short*)p;          p += (size_t)NN * BB * 2;
    unsigned short* x_bf  = (unsigned short*)p;          p += (size_t)BB * KDIM * 2;
    float*          part  = (float*)p;                   // KS*1024*BB floats

    xbf_kernel<<<256, 256, 0, stream>>>(x, (unsigned*)x_bf);
    xproj_mfma<<<864, 256, 0, stream>>>(w_in, b_in, (const short*)x_bf, xp_bf, hA);

    const unsigned* hp = (const unsigned*)hA;
    unsigned* hn = (unsigned*)hB;
    for (int s = 0; s < 29; ++s) {          // 29 odd -> final state in hB
        step_kernel<<<1152, 256, 0, stream>>>(hp, (const unsigned*)xp_bf, w_local, hn);
        unsigned* t = (unsigned*)hp; hp = hn; hn = t;
    }

    transpose_kernel<<<dim3(216, 4), 256, 0, stream>>>(hp, (unsigned*)hT);
    outgemm_mfma<<<dim3(KS, 8), 512, 0, stream>>>(w_out, (const short*)hT, part);
    reduce_kernel<<<ODIM, 256, 0, stream>>>(part, b_out, out);
}

// Round 8
// 547.286 us; speedup vs baseline: 1.8021x; 1.0119x over previous
//
#include <hip/hip_runtime.h>
#include <hip/hip_bf16.h>

#define NN   13824     // 24^3 neurons
#define BB   256       // batch
#define KDIM 512       // input dim
#define ODIM 1000      // output dim
#define CUBE 24
#define KS   16        // out-gemm split-K
#define XSTR 516       // xproj LDS A row stride in shorts (258 dw, %32=2 -> 16 start banks)
#define OSTR 452       // outgemm LDS A row stride in shorts (226 dw, %32=2 -> 16 start banks)

typedef short bf8 __attribute__((ext_vector_type(8)));     // 8 bf16 (4 VGPRs)
typedef float f32x4 __attribute__((ext_vector_type(4)));   // MFMA acc

__device__ __forceinline__ float fast_tanh(float a) {
    float e = __expf(2.0f * a);
    return 1.0f - 2.0f / (e + 1.0f);
}
__device__ __forceinline__ float bf_lo(unsigned u) { return __uint_as_float(u << 16); }
__device__ __forceinline__ float bf_hi(unsigned u) { return __uint_as_float(u & 0xffff0000u); }
__device__ __forceinline__ unsigned short bf_rne(float f) {
    unsigned u = __float_as_uint(f);
    u += 0x7fffu + ((u >> 16) & 1u);
    return (unsigned short)(u >> 16);
}
// packed fp32x2 -> bf16x2 via v_cvt_pk_bf16_f32 (one inst on gfx950)
__device__ __forceinline__ unsigned pk_bf16(float lo, float hi) {
    union { __hip_bfloat162 h; unsigned u; } cv;
    cv.h = __float22bfloat162_rn(make_float2(lo, hi));
    return cv.u;
}

// ---------------------------------------------------------------------------
// x (fp32 [256][512]) -> x_bf (bf16 packed dwords)
// ---------------------------------------------------------------------------
__global__ __launch_bounds__(256) void xbf_kernel(
    const float* __restrict__ x, unsigned* __restrict__ xb)
{
    int i = blockIdx.x * 256 + threadIdx.x;
    float2 v = *(const float2*)&x[(size_t)i * 2];
    xb[i] = pk_bf16(v.x, v.y);
}

// ---------------------------------------------------------------------------
// xproj v2b: LDS-staged A panel, whole-row reads. XSTR 520->516 (dw-stride
// 258%32=2 -> the 16-lane ds_read_b128 covers 16 start banks, 8 dw/bank =
// conflict-free minimum; 520 was %32=4 -> 8 banks = 8-way conflict).
// ---------------------------------------------------------------------------
__global__ __launch_bounds__(256) void xproj_mfma(
    const float* __restrict__ w_in, const float* __restrict__ bias,
    const short* __restrict__ xbf, unsigned short* __restrict__ xp,
    unsigned short* __restrict__ h1)
{
    __shared__ unsigned short As[16 * XSTR];
    const int tid = threadIdx.x, w = tid >> 6, lane = tid & 63;
    const int quad = lane >> 4, l16 = lane & 15;
    const int n0 = blockIdx.x * 16;

    // ---- stage A: 4 whole rows per wave, 1KB-contiguous reads ----
#pragma unroll
    for (int rr = 0; rr < 4; ++rr) {
        const int row = w * 4 + rr;
        const float* __restrict__ src = &w_in[(size_t)(n0 + row) * KDIM];
#pragma unroll
        for (int c = 0; c < 2; ++c) {
            const int col = c * 256 + lane * 4;
            float4 v = *(const float4*)&src[col];
            uint2 pk2 = make_uint2(pk_bf16(v.x, v.y), pk_bf16(v.z, v.w));
            *(uint2*)&As[row * XSTR + col] = pk2;
        }
    }
    __syncthreads();

    f32x4 acc[4] = {};

    int ka = quad * 8;
    bf8 bb[4];
#pragma unroll
    for (int j = 0; j < 4; ++j)
        bb[j] = *(const bf8*)&xbf[(size_t)(w * 64 + j * 16 + l16) * KDIM + ka];

    for (int it = 0; it < 16; ++it) {
        bf8 nb[4] = {};
        if (it < 15) {
            const int nka = ka + 32;
#pragma unroll
            for (int j = 0; j < 4; ++j)
                nb[j] = *(const bf8*)&xbf[(size_t)(w * 64 + j * 16 + l16) * KDIM + nka];
        }
        bf8 af = *(const bf8*)&As[l16 * XSTR + it * 32 + quad * 8];
#pragma unroll
        for (int j = 0; j < 4; ++j)
            acc[j] = __builtin_amdgcn_mfma_f32_16x16x32_bf16(af, bb[j], acc[j], 0, 0, 0);
#pragma unroll
        for (int j = 0; j < 4; ++j) bb[j] = nb[j];
        ka += 32;
    }

#pragma unroll
    for (int j = 0; j < 4; ++j) {
        const int b = w * 64 + j * 16 + l16;
#pragma unroll
        for (int r = 0; r < 4; ++r) {
            const int n = n0 + quad * 4 + r;
            const float v = acc[j][r] + bias[n];
            xp[(size_t)n * BB + b] = bf_rne(v);
            h1[(size_t)n * BB + b] = bf_rne(fast_tanh(v));
        }
    }
}

// ---------------------------------------------------------------------------
// Recurrent step v6 (round-2/5 proven best, ~14.9us/step): float2 ring-5,
// x-chunk 6, 4-wave blocks pairing two adjacent y-lines (L1 sharing).
// 1152 blocks, bid&7 == z/3 -> XCD L2 slab pinning. Step is latency/TLP-
// bound (needs 18 waves/CU); halo-LDS (r6) and MLP tweaks (r3) both failed.
// ---------------------------------------------------------------------------
__device__ __forceinline__ void load_plane_f2(
    const unsigned* __restrict__ h32, int z, int y, int xx, int dof, float2* w9)
{
#pragma unroll
    for (int j = 0; j < 9; ++j) {
        const int dz = j / 3 - 1, dy = j % 3 - 1;
        const int zz = z + dz, yy = y + dy;
        const bool valid = (xx >= 0) & (xx < CUBE) & (zz >= 0) & (zz < CUBE) &
                           (yy >= 0) & (yy < CUBE);   // wave-uniform
        unsigned v = 0u;
        if (valid) v = h32[(size_t)((zz * 24 + yy) * 24 + xx) * 128 + dof];
        w9[j] = make_float2(bf_lo(v), bf_hi(v));
    }
}

__global__ __launch_bounds__(256) void step_kernel(
    const unsigned* __restrict__ hprev, const unsigned* __restrict__ xp,
    const float* __restrict__ wl, unsigned* __restrict__ hnext)
{
    const int tid  = threadIdx.x;
    const int wid  = __builtin_amdgcn_readfirstlane(tid >> 6);  // 0..3
    const int wvb  = wid & 1;          // batch half
    const int yoff = wid >> 1;         // y within the pair
    const int lane = tid & 63;

    const int bid   = blockIdx.x;
    const int zhi   = bid & 7;
    const int inner = bid >> 3;       // 0..143
    const int yp    = inner % 12;
    const int r     = inner / 12;     // 0..11
    const int xc    = r & 3;
    const int zlo   = r >> 2;
    const int z     = zhi * 3 + zlo;
    const int y     = yp * 2 + yoff;

    const int x0   = xc * 6;
    const int dof  = wvb * 64 + lane;  // dword offset (2 batch elems)

    float2 win[5][9];
    load_plane_f2(hprev, z, y, x0 - 1, dof, win[0]);
    load_plane_f2(hprev, z, y, x0,     dof, win[1]);
    load_plane_f2(hprev, z, y, x0 + 1, dof, win[2]);
    load_plane_f2(hprev, z, y, x0 + 2, dof, win[3]);

#pragma unroll
    for (int xi = 0; xi < 6; ++xi) {
        const int x = x0 + xi;
        if (xi <= 3)
            load_plane_f2(hprev, z, y, x + 3, dof, win[(xi + 4) % 5]);

        const int n = (z * 24 + y) * 24 + x;          // wave-uniform
        const float* __restrict__ wn = &wl[(size_t)n * 27];
        const unsigned xpv = xp[(size_t)n * 128 + dof];
        float2 acc = make_float2(bf_lo(xpv), bf_hi(xpv));

        const float2* pm = win[xi % 5];
        const float2* pc = win[(xi + 1) % 5];
        const float2* pp = win[(xi + 2) % 5];
#pragma unroll
        for (int j = 0; j < 9; ++j) {
            const float w0 = wn[3 * j + 0];
            const float w1 = wn[3 * j + 1];
            const float w2 = wn[3 * j + 2];
            acc.x += w0 * pm[j].x + w1 * pc[j].x + w2 * pp[j].x;
            acc.y += w0 * pm[j].y + w1 * pc[j].y + w2 * pp[j].y;
        }
        hnext[(size_t)n * 128 + dof] = pk_bf16(fast_tanh(acc.x), fast_tanh(acc.y));
    }
}

// ---------------------------------------------------------------------------
// Transpose h[k][b] -> hT[b][k] (bf16), 64x64 tiles via LDS.
// ---------------------------------------------------------------------------
__global__ __launch_bounds__(256) void transpose_kernel(
    const unsigned* __restrict__ h32, unsigned* __restrict__ hT32)
{
    __shared__ unsigned short T[64][66];
    const int tid = threadIdx.x;
    const int rr = tid >> 2, g = tid & 3;
    const int k0 = blockIdx.x * 64, b0 = blockIdx.y * 64;
#pragma unroll
    for (int i = 0; i < 8; ++i) {
        unsigned d = h32[(size_t)(k0 + rr) * 128 + b0 / 2 + g * 8 + i];
        const int bl = (g * 8 + i) * 2;
        T[bl][rr]     = (unsigned short)(d & 0xffffu);
        T[bl + 1][rr] = (unsigned short)(d >> 16);
    }
    __syncthreads();
#pragma unroll
    for (int i = 0; i < 8; ++i) {
        const int kl = (g * 8 + i) * 2;
        unsigned d = (unsigned)T[rr][kl] | ((unsigned)T[rr][kl + 1] << 16);
        hT32[(size_t)(b0 + rr) * (NN / 2) + k0 / 2 + g * 8 + i] = d;
    }
}

// ---------------------------------------------------------------------------
// Output GEMM v8: v7's o-tile-128 B-reuse (216 strided-B instrs/CU per
// 128o x 128b -- half of v6b per output) with the half-idle-GPU bug fixed:
// split batch across blockIdx.z -> grid (16 K, 8 o, 2 b-half) = 256 blocks,
// 8 waves each = all 256 CUs at 8 waves/CU. Wave w owns b = z*128+w*16
// (1 B-frag/kc); all 8 waves share the 128-row LDS A panel (staged in two
// 448/416-K phases, 114KB live). Same-K blocks share an XCD (linear id
// mod 8 = blockIdx.x mod 8) -> hT K-slice L2-resident; the two b-halves of
// an (K,o) pair also share the XCD -> 2nd A-stage read is L2-hit.
// OSTR 456->452: dw-stride 226%32=2 -> 16 distinct row-start banks ->
// ds_read_b128 A-frags conflict-free (456 was 8-way; 884K conflict cycles).
// ---------------------------------------------------------------------------
__global__ __launch_bounds__(512) void outgemm_mfma(
    const float* __restrict__ wout, const short* __restrict__ hT,
    float* __restrict__ part)
{
    __shared__ unsigned short As[128 * OSTR];
    const int tid = threadIdx.x, w = tid >> 6, lane = tid & 63;
    const int quad = lane >> 4, l16 = lane & 15;
    const int kb = blockIdx.x * (NN / KS);    // 864-wide K chunk
    const int o0 = blockIdx.y * 128;
    const int b0 = blockIdx.z * 128 + w * 16; // 16 b-rows per wave

    f32x4 acc[8] = {};

#pragma unroll 1
    for (int ph = 0; ph < 2; ++ph) {
        const int poff  = ph ? 448 : 0;       // K offset of this phase
        const int pcols = ph ? 416 : 448;     // floats per row this phase
        const int pkc   = ph ? 13 : 14;       // kc count (x32 = pcols)
        if (ph) __syncthreads();              // compute done before re-stage

        // ---- stage A: 16 rows/wave, 1KB-contiguous global reads ----
#pragma unroll 4
        for (int rr = 0; rr < 16; ++rr) {
            const int row = w * 16 + rr;
            const int o = o0 + row;
            const float* __restrict__ src = &wout[(size_t)o * NN + kb + poff];
#pragma unroll
            for (int c = 0; c < 2; ++c) {
                const int col = c * 256 + lane * 4;
                if (col < pcols) {
                    float4 v = {0.f, 0.f, 0.f, 0.f};
                    if (o < ODIM) v = *(const float4*)&src[col];
                    *(uint2*)&As[row * OSTR + col] =
                        make_uint2(pk_bf16(v.x, v.y), pk_bf16(v.z, v.w));
                }
            }
        }
        __syncthreads();

        // ---- compute pkc kc's; depth-1 B prefetch (dynamic loop) ----
        bf8 bb;
        {
            const int ka = kb + poff + quad * 8;
            bb = *(const bf8*)&hT[(size_t)(b0 + l16) * NN + ka];
        }
        for (int kc = 0; kc < pkc; ++kc) {
            bf8 nb = {};
            if (kc + 1 < pkc) {
                const int ka = kb + poff + (kc + 1) * 32 + quad * 8;
                nb = *(const bf8*)&hT[(size_t)(b0 + l16) * NN + ka];
            }
            const int cs = kc * 32 + quad * 8;   // short offset within row
#pragma unroll
            for (int t = 0; t < 8; ++t) {
                bf8 af = *(const bf8*)&As[(t * 16 + l16) * OSTR + cs];
                acc[t] = __builtin_amdgcn_mfma_f32_16x16x32_bf16(af, bb, acc[t], 0, 0, 0);
            }
            bb = nb;
        }
    }

    // ---- epilogue ----
#pragma unroll
    for (int t = 0; t < 8; ++t) {
        const int b = b0 + l16;
#pragma unroll
        for (int r = 0; r < 4; ++r) {
            const int o = o0 + t * 16 + quad * 4 + r;
            part[((size_t)blockIdx.x * 1024 + o) * BB + b] = acc[t][r];
        }
    }
}

// out[b*1000+o] = bias[o] + sum_kc part[kc][o][b]; block per o, lanes = b.
__global__ __launch_bounds__(256) void reduce_kernel(
    const float* __restrict__ part, const float* __restrict__ bias,
    float* __restrict__ out)
{
    const int o = blockIdx.x, b = threadIdx.x;
    float s = bias[o];
#pragma unroll
    for (int kc = 0; kc < KS; ++kc)
        s += part[((size_t)kc * 1024 + o) * BB + b];
    out[(size_t)b * ODIM + o] = s;
}

extern "C" void kernel_launch(void* const* d_in, const int* in_sizes, int n_in,
                              void* d_out, int out_size, void* d_ws, size_t ws_size,
                              hipStream_t stream)
{
    const float* x       = (const float*)d_in[0];
    const float* w_in    = (const float*)d_in[1];
    const float* b_in    = (const float*)d_in[2];
    const float* w_local = (const float*)d_in[3];
    const float* w_out   = (const float*)d_in[4];
    const float* b_out   = (const float*)d_in[5];
    float* out = (float*)d_out;

    char* p = (char*)d_ws;
    unsigned short* xp_bf = (unsigned short*)p;          p += (size_t)NN * BB * 2;
    unsigned short* hA    = (unsigned short*)p;          p += (size_t)NN * BB * 2;
    unsigned short* hB    = (unsigned short*)p;          p += (size_t)NN * BB * 2;
    unsigned short* hT    = (unsigned short*)p;          p += (size_t)NN * BB * 2;
    unsigned short* x_bf  = (unsigned short*)p;          p += (size_t)BB * KDIM * 2;
    float*          part  = (float*)p;                   // KS*1024*BB floats

    xbf_kernel<<<256, 256, 0, stream>>>(x, (unsigned*)x_bf);
    xproj_mfma<<<864, 256, 0, stream>>>(w_in, b_in, (const short*)x_bf, xp_bf, hA);

    const unsigned* hp = (const unsigned*)hA;
    unsigned* hn = (unsigned*)hB;
    for (int s = 0; s < 29; ++s) {          // 29 odd -> final state in hB
        step_kernel<<<1152, 256, 0, stream>>>(hp, (const unsigned*)xp_bf, w_local, hn);
        unsigned* t = (unsigned*)hp; hp = hn; hn = t;
    }

    transpose_kernel<<<dim3(216, 4), 256, 0, stream>>>(hp, (unsigned*)hT);
    outgemm_mfma<<<dim3(KS, 8, 2), 512, 0, stream>>>(w_out, (const short*)hT, part);
    reduce_kernel<<<ODIM, 256, 0, stream>>>(part, b_out, out);
}

// Round 9
// 537.266 us; speedup vs baseline: 1.8357x; 1.0187x over previous
//
#include <hip/hip_runtime.h>
#include <hip/hip_bf16.h>

#define NN   13824     // 24^3 neurons
#define BB   256       // batch
#define KDIM 512       // input dim
#define ODIM 1000      // output dim
#define CUBE 24
#define KS   16        // out-gemm split-K
#define XSTR 516       // xproj LDS A row stride in shorts (258 dw, %32=2 -> 16 start banks)
#define OSTR 452       // outgemm LDS A row stride in shorts (226 dw, %32=2 -> 16 start banks)

typedef short bf8 __attribute__((ext_vector_type(8)));     // 8 bf16 (4 VGPRs)
typedef float f32x4 __attribute__((ext_vector_type(4)));   // MFMA acc

__device__ __forceinline__ float fast_tanh(float a) {
    float e = __expf(2.0f * a);
    return 1.0f - 2.0f / (e + 1.0f);
}
__device__ __forceinline__ float bf_lo(unsigned u) { return __uint_as_float(u << 16); }
__device__ __forceinline__ float bf_hi(unsigned u) { return __uint_as_float(u & 0xffff0000u); }
__device__ __forceinline__ unsigned short bf_rne(float f) {
    unsigned u = __float_as_uint(f);
    u += 0x7fffu + ((u >> 16) & 1u);
    return (unsigned short)(u >> 16);
}
// packed fp32x2 -> bf16x2 via v_cvt_pk_bf16_f32 (one inst on gfx950)
__device__ __forceinline__ unsigned pk_bf16(float lo, float hi) {
    union { __hip_bfloat162 h; unsigned u; } cv;
    cv.h = __float22bfloat162_rn(make_float2(lo, hi));
    return cv.u;
}

// ---------------------------------------------------------------------------
// x (fp32 [256][512]) -> x_bf (bf16 packed dwords)
// ---------------------------------------------------------------------------
__global__ __launch_bounds__(256) void xbf_kernel(
    const float* __restrict__ x, unsigned* __restrict__ xb)
{
    int i = blockIdx.x * 256 + threadIdx.x;
    float2 v = *(const float2*)&x[(size_t)i * 2];
    xb[i] = pk_bf16(v.x, v.y);
}

// ---------------------------------------------------------------------------
// xproj v2b (round-8, passed): LDS-staged A panel, whole-row reads,
// conflict-free stride 516.
// ---------------------------------------------------------------------------
__global__ __launch_bounds__(256) void xproj_mfma(
    const float* __restrict__ w_in, const float* __restrict__ bias,
    const short* __restrict__ xbf, unsigned short* __restrict__ xp,
    unsigned short* __restrict__ h1)
{
    __shared__ unsigned short As[16 * XSTR];
    const int tid = threadIdx.x, w = tid >> 6, lane = tid & 63;
    const int quad = lane >> 4, l16 = lane & 15;
    const int n0 = blockIdx.x * 16;

    // ---- stage A: 4 whole rows per wave, 1KB-contiguous reads ----
#pragma unroll
    for (int rr = 0; rr < 4; ++rr) {
        const int row = w * 4 + rr;
        const float* __restrict__ src = &w_in[(size_t)(n0 + row) * KDIM];
#pragma unroll
        for (int c = 0; c < 2; ++c) {
            const int col = c * 256 + lane * 4;
            float4 v = *(const float4*)&src[col];
            uint2 pk2 = make_uint2(pk_bf16(v.x, v.y), pk_bf16(v.z, v.w));
            *(uint2*)&As[row * XSTR + col] = pk2;
        }
    }
    __syncthreads();

    f32x4 acc[4] = {};

    int ka = quad * 8;
    bf8 bb[4];
#pragma unroll
    for (int j = 0; j < 4; ++j)
        bb[j] = *(const bf8*)&xbf[(size_t)(w * 64 + j * 16 + l16) * KDIM + ka];

    for (int it = 0; it < 16; ++it) {
        bf8 nb[4] = {};
        if (it < 15) {
            const int nka = ka + 32;
#pragma unroll
            for (int j = 0; j < 4; ++j)
                nb[j] = *(const bf8*)&xbf[(size_t)(w * 64 + j * 16 + l16) * KDIM + nka];
        }
        bf8 af = *(const bf8*)&As[l16 * XSTR + it * 32 + quad * 8];
#pragma unroll
        for (int j = 0; j < 4; ++j)
            acc[j] = __builtin_amdgcn_mfma_f32_16x16x32_bf16(af, bb[j], acc[j], 0, 0, 0);
#pragma unroll
        for (int j = 0; j < 4; ++j) bb[j] = nb[j];
        ka += 32;
    }

#pragma unroll
    for (int j = 0; j < 4; ++j) {
        const int b = w * 64 + j * 16 + l16;
#pragma unroll
        for (int r = 0; r < 4; ++r) {
            const int n = n0 + quad * 4 + r;
            const float v = acc[j][r] + bias[n];
            xp[(size_t)n * BB + b] = bf_rne(v);
            h1[(size_t)n * BB + b] = bf_rne(fast_tanh(v));
        }
    }
}

// ---------------------------------------------------------------------------
// Recurrent step v9: v6 inner loop VERBATIM; shape change only.
// y-QUAD blocks (4 waves = 4 adjacent y-lines, one batch half per block):
// per-plane L1 union 18 half-rows / 4 outputs vs v6's 12 full-rows / 6 ->
// beyond-L1 h traffic 28 -> 24 MB/step. x-chunk 4 (ring-5 still works:
// prologue 4 planes + 2 in-loop). xp preloaded (prologue MLP; r3's version
// was confounded with the packed-ring change). Grid 24z*6yq*6xc*2half =
// 1728 blocks; bid&7 = z/3 -> XCD slab pinning (HW round-robin by bid%8).
// NOT wave-count-bound (r3: +25% co-resident TLP = neutral), so no
// launch_bounds cap; VGPR ~114 -> 4 waves/SIMD co-resident, as v6.
// ---------------------------------------------------------------------------
__device__ __forceinline__ void load_plane_f2(
    const unsigned* __restrict__ h32, int z, int y, int xx, int dof, float2* w9)
{
#pragma unroll
    for (int j = 0; j < 9; ++j) {
        const int dz = j / 3 - 1, dy = j % 3 - 1;
        const int zz = z + dz, yy = y + dy;
        const bool valid = (xx >= 0) & (xx < CUBE) & (zz >= 0) & (zz < CUBE) &
                           (yy >= 0) & (yy < CUBE);   // wave-uniform
        unsigned v = 0u;
        if (valid) v = h32[(size_t)((zz * 24 + yy) * 24 + xx) * 128 + dof];
        w9[j] = make_float2(bf_lo(v), bf_hi(v));
    }
}

__global__ __launch_bounds__(256) void step_kernel(
    const unsigned* __restrict__ hprev, const unsigned* __restrict__ xp,
    const float* __restrict__ wl, unsigned* __restrict__ hnext)
{
    const int tid  = threadIdx.x;
    const int wid  = __builtin_amdgcn_readfirstlane(tid >> 6);  // y in quad
    const int lane = tid & 63;

    const int bid   = blockIdx.x;
    const int zhi   = bid & 7;        // XCD slab
    const int inner = bid >> 3;       // 0..215
    const int half  = inner & 1;
    const int u     = inner >> 1;     // 0..107
    const int xc    = u % 6;
    const int u2    = u / 6;          // 0..17
    const int yq    = u2 % 6;
    const int zlo   = u2 / 6;         // 0..2
    const int z     = zhi * 3 + zlo;
    const int y     = yq * 4 + wid;

    const int x0   = xc * 4;
    const int dof  = half * 64 + lane;  // dword offset (2 batch elems)
    const int n0   = (z * 24 + y) * 24 + x0;

    float2 win[5][9];
    load_plane_f2(hprev, z, y, x0 - 1, dof, win[0]);
    load_plane_f2(hprev, z, y, x0,     dof, win[1]);
    load_plane_f2(hprev, z, y, x0 + 1, dof, win[2]);
    load_plane_f2(hprev, z, y, x0 + 2, dof, win[3]);

    unsigned xpv[4];
#pragma unroll
    for (int xi = 0; xi < 4; ++xi)
        xpv[xi] = xp[(size_t)(n0 + xi) * 128 + dof];

#pragma unroll
    for (int xi = 0; xi < 4; ++xi) {
        const int x = x0 + xi;
        if (xi <= 1)
            load_plane_f2(hprev, z, y, x + 3, dof, win[(xi + 4) % 5]);

        const int n = n0 + xi;                        // wave-uniform
        const float* __restrict__ wn = &wl[(size_t)n * 27];
        float2 acc = make_float2(bf_lo(xpv[xi]), bf_hi(xpv[xi]));

        const float2* pm = win[xi % 5];
        const float2* pc = win[(xi + 1) % 5];
        const float2* pp = win[(xi + 2) % 5];
#pragma unroll
        for (int j = 0; j < 9; ++j) {
            const float w0 = wn[3 * j + 0];
            const float w1 = wn[3 * j + 1];
            const float w2 = wn[3 * j + 2];
            acc.x += w0 * pm[j].x + w1 * pc[j].x + w2 * pp[j].x;
            acc.y += w0 * pm[j].y + w1 * pc[j].y + w2 * pp[j].y;
        }
        hnext[(size_t)n * 128 + dof] = pk_bf16(fast_tanh(acc.x), fast_tanh(acc.y));
    }
}

// ---------------------------------------------------------------------------
// Transpose h[k][b] -> hT[b][k] (bf16), 64x64 tiles via LDS.
// ---------------------------------------------------------------------------
__global__ __launch_bounds__(256) void transpose_kernel(
    const unsigned* __restrict__ h32, unsigned* __restrict__ hT32)
{
    __shared__ unsigned short T[64][66];
    const int tid = threadIdx.x;
    const int rr = tid >> 2, g = tid & 3;
    const int k0 = blockIdx.x * 64, b0 = blockIdx.y * 64;
#pragma unroll
    for (int i = 0; i < 8; ++i) {
        unsigned d = h32[(size_t)(k0 + rr) * 128 + b0 / 2 + g * 8 + i];
        const int bl = (g * 8 + i) * 2;
        T[bl][rr]     = (unsigned short)(d & 0xffffu);
        T[bl + 1][rr] = (unsigned short)(d >> 16);
    }
    __syncthreads();
#pragma unroll
    for (int i = 0; i < 8; ++i) {
        const int kl = (g * 8 + i) * 2;
        unsigned d = (unsigned)T[rr][kl] | ((unsigned)T[rr][kl + 1] << 16);
        hT32[(size_t)(b0 + rr) * (NN / 2) + k0 / 2 + g * 8 + i] = d;
    }
}

// ---------------------------------------------------------------------------
// Output GEMM v9 = v8 geometry (full GPU, o-tile 128, conflict-free LDS) +
// depth-2 prefetch on the B stream ONLY (named s0/s1, step-2 dynamic loop;
// 8 extra VGPR -- small enough that the compiler has no pressure motive to
// collapse it, unlike r3's full A+B 2-stage). Theory: at 1 block/CU
// (2 waves/SIMD) each kc exposes one B-load round-trip that depth-1 can't
// cover; depth-2 halves the exposed latency per kc.
// ---------------------------------------------------------------------------
__global__ __launch_bounds__(512) void outgemm_mfma(
    const float* __restrict__ wout, const short* __restrict__ hT,
    float* __restrict__ part)
{
    __shared__ unsigned short As[128 * OSTR];
    const int tid = threadIdx.x, w = tid >> 6, lane = tid & 63;
    const int quad = lane >> 4, l16 = lane & 15;
    const int kb = blockIdx.x * (NN / KS);    // 864-wide K chunk
    const int o0 = blockIdx.y * 128;
    const int b0 = blockIdx.z * 128 + w * 16; // 16 b-rows per wave

    const short* __restrict__ brow = &hT[(size_t)(b0 + l16) * NN];

    f32x4 acc[8] = {};

#pragma unroll 1
    for (int ph = 0; ph < 2; ++ph) {
        const int poff  = ph ? 448 : 0;       // K offset of this phase
        const int pcols = ph ? 416 : 448;     // floats per row this phase
        const int pkc   = ph ? 13 : 14;       // kc count (x32 = pcols)
        if (ph) __syncthreads();              // compute done before re-stage

        // ---- stage A: 16 rows/wave, 1KB-contiguous global reads ----
#pragma unroll 4
        for (int rr = 0; rr < 16; ++rr) {
            const int row = w * 16 + rr;
            const int o = o0 + row;
            const float* __restrict__ src = &wout[(size_t)o * NN + kb + poff];
#pragma unroll
            for (int c = 0; c < 2; ++c) {
                const int col = c * 256 + lane * 4;
                if (col < pcols) {
                    float4 v = {0.f, 0.f, 0.f, 0.f};
                    if (o < ODIM) v = *(const float4*)&src[col];
                    *(uint2*)&As[row * OSTR + col] =
                        make_uint2(pk_bf16(v.x, v.y), pk_bf16(v.z, v.w));
                }
            }
        }
        __syncthreads();

        // ---- compute pkc kc's; depth-2 B prefetch (named stages) ----
        const int kab = kb + poff + quad * 8;
        bf8 s0 = *(const bf8*)&brow[kab];
        bf8 s1 = *(const bf8*)&brow[kab + 32];

        for (int kc = 0; kc < pkc; kc += 2) {
            // even kc: consume s0, refill s0 for kc+2
            {
                const int cs = kc * 32 + quad * 8;
                bf8 cur = s0;
                if (kc + 2 < pkc) s0 = *(const bf8*)&brow[kab + (kc + 2) * 32];
#pragma unroll
                for (int t = 0; t < 8; ++t) {
                    bf8 af = *(const bf8*)&As[(t * 16 + l16) * OSTR + cs];
                    acc[t] = __builtin_amdgcn_mfma_f32_16x16x32_bf16(af, cur, acc[t], 0, 0, 0);
                }
            }
            // odd kc+1: consume s1, refill s1 for kc+3
            if (kc + 1 < pkc) {
                const int cs = (kc + 1) * 32 + quad * 8;
                bf8 cur = s1;
                if (kc + 3 < pkc) s1 = *(const bf8*)&brow[kab + (kc + 3) * 32];
#pragma unroll
                for (int t = 0; t < 8; ++t) {
                    bf8 af = *(const bf8*)&As[(t * 16 + l16) * OSTR + cs];
                    acc[t] = __builtin_amdgcn_mfma_f32_16x16x32_bf16(af, cur, acc[t], 0, 0, 0);
                }
            }
        }
    }

    // ---- epilogue ----
#pragma unroll
    for (int t = 0; t < 8; ++t) {
        const int b = b0 + l16;
#pragma unroll
        for (int r = 0; r < 4; ++r) {
            const int o = o0 + t * 16 + quad * 4 + r;
            part[((size_t)blockIdx.x * 1024 + o) * BB + b] = acc[t][r];
        }
    }
}

// out[b*1000+o] = bias[o] + sum_kc part[kc][o][b]; block per o, lanes = b.
__global__ __launch_bounds__(256) void reduce_kernel(
    const float* __restrict__ part, const float* __restrict__ bias,
    float* __restrict__ out)
{
    const int o = blockIdx.x, b = threadIdx.x;
    float s = bias[o];
#pragma unroll
    for (int kc = 0; kc < KS; ++kc)
        s += part[((size_t)kc * 1024 + o) * BB + b];
    out[(size_t)b * ODIM + o] = s;
}

extern "C" void kernel_launch(void* const* d_in, const int* in_sizes, int n_in,
                              void* d_out, int out_size, void* d_ws, size_t ws_size,
                              hipStream_t stream)
{
    const float* x       = (const float*)d_in[0];
    const float* w_in    = (const float*)d_in[1];
    const float* b_in    = (const float*)d_in[2];
    const float* w_local = (const float*)d_in[3];
    const float* w_out   = (const float*)d_in[4];
    const float* b_out   = (const float*)d_in[5];
    float* out = (float*)d_out;

    char* p = (char*)d_ws;
    unsigned short* xp_bf = (unsigned short*)p;          p += (size_t)NN * BB * 2;
    unsigned short* hA    = (unsigned short*)p;          p += (size_t)NN * BB * 2;
    unsigned short* hB    = (unsigned short*)p;          p += (size_t)NN * BB * 2;
    unsigned short* hT    = (unsigned short*)p;          p += (size_t)NN * BB * 2;
    unsigned short* x_bf  = (unsigned short*)p;          p += (size_t)BB * KDIM * 2;
    float*          part  = (float*)p;                   // KS*1024*BB floats

    xbf_kernel<<<256, 256, 0, stream>>>(x, (unsigned*)x_bf);
    xproj_mfma<<<864, 256, 0, stream>>>(w_in, b_in, (const short*)x_bf, xp_bf, hA);

    const unsigned* hp = (const unsigned*)hA;
    unsigned* hn = (unsigned*)hB;
    for (int s = 0; s < 29; ++s) {          // 29 odd -> final state in hB
        step_kernel<<<1728, 256, 0, stream>>>(hp, (const unsigned*)xp_bf, w_local, hn);
        unsigned* t = (unsigned*)hp; hp = hn; hn = t;
    }

    transpose_kernel<<<dim3(216, 4), 256, 0, stream>>>(hp, (unsigned*)hT);
    outgemm_mfma<<<dim3(KS, 8, 2), 512, 0, stream>>>(w_out, (const short*)hT, part);
    reduce_kernel<<<ODIM, 256, 0, stream>>>(part, b_out, out);
}